// Round 3
// baseline (154.763 us; speedup 1.0000x reference)
//
#include <hip/hip_runtime.h>
#include <stdint.h>

// Problem constants (fixed by setup_inputs)
#define NB 16
#define NTF 4096      // frames T
#define ND 512        // feature dim D
#define NS 8192       // note_size (= 2*T)
#define NCOL 40       // 5 + 10 + 25 output columns

typedef float v4f __attribute__((ext_vector_type(4)));
typedef float v2f __attribute__((ext_vector_type(2)));

// LDS map (bytes):
//   [0, 81920)        W [40][512] f32 (staged once)
//   [81920, 147456)   x buffers: wave w, parity p at 81920 + (w*2+p)*8192
// after main loop (barrier), [0, 90112) is reused:
//   A [256][44] f32 at 0, B [256][44] f32 at 45056
#define LDS_BYTES 147456
#define XBUF_OFF  81920
#define BBUF_OFF  45056
#define ACC_STRIDE 44     // 44 % 8 == 4, stride 176B -> all 8 bank-quads hit

// Pack Wg[512][5], Wt[512][10], Wf[512][25] -> Wp[40][512]
extern "C" __global__ void pack_w_kernel(const float* __restrict__ Wg,
                                         const float* __restrict__ Wt,
                                         const float* __restrict__ Wf,
                                         float* __restrict__ Wp)
{
    int i = blockIdx.x * 256 + threadIdx.x;   // i = c*512 + d
    if (i >= NCOL * ND) return;
    int c = i >> 9, d = i & (ND - 1);
    float v;
    if (c < 5)       v = Wg[d * 5  + c];
    else if (c < 15) v = Wt[d * 10 + (c - 5)];
    else             v = Wf[d * 25 + (c - 15)];
    Wp[i] = v;
}

// global_load_lds: LDS dest is WAVE-UNIFORM base (HW adds lane*16); global src is per-lane.
#define GLDS(gp, lp) __builtin_amdgcn_global_load_lds( \
    (const __attribute__((address_space(1))) unsigned int*)(gp), \
    (__attribute__((address_space(3))) unsigned int*)(lp), 16, 0, 0)

// Block: 4 waves, 256 rows. Wave w owns d-quarter [w*128,(w+1)*128).
// Lane l accumulates rows {l, l+64, l+128, l+192} (R=4): each uniform W read
// feeds 4 FMAs -> 4x fewer LDS reads than lane=row structures.
extern "C" __global__ void __launch_bounds__(256, 1)
hier_main(const float* __restrict__ x,
          const float* __restrict__ bg, const float* __restrict__ bt,
          const float* __restrict__ bf,
          const float* __restrict__ Wp, float* __restrict__ out)
{
    __shared__ __align__(16) char smem[LDS_BYTES];
    float* Wl = (float*)smem;

    const int t    = threadIdx.x;
    const int lane = t & 63;
    const int w    = t >> 6;
    const int row0 = blockIdx.x * 256;

    float acc[4][NCOL];
#pragma unroll
    for (int r = 0; r < 4; ++r)
#pragma unroll
        for (int c = 0; c < NCOL; ++c) acc[r][c] = 0.f;

    // ---- prologue: stage W (80KB = 5120 x 16B slots, 20 instrs/wave, linear) ----
#pragma unroll
    for (int j = 0; j < 20; ++j) {
        const int sbase = (j * 4 + w) * 64;         // wave-uniform slot base
        const int slot  = sbase + lane;             // per-lane global slot
        GLDS(Wp + (size_t)slot * 4, (char*)smem + (size_t)sbase * 16);
    }

    // x chunk stage: 8KB = 256 rows x 8 floats; slot = q*256 + row (q-major ->
    // per-(q,r) reads land on all 8 bank-quads, conflict-free at the 8-cyc floor)
    auto stage_x = [&](int ch, int p) {
        char* dst = (char*)smem + XBUF_OFF + (size_t)((w * 2 + p) * 8192);
        const int dbase = w * 128 + ch * 8;
#pragma unroll
        for (int i = 0; i < 8; ++i) {
            const int s  = i * 64 + lane;           // slot 0..511
            const int q  = s >> 8;                  // 0..1
            const int rr = s & 255;                 // row in block
            GLDS(x + (size_t)(row0 + rr) * ND + dbase + q * 4,
                 dst + (size_t)(i * 64) * 16);
        }
    };

    stage_x(0, 0);
    stage_x(1, 1);
    __builtin_amdgcn_sched_barrier(0);
    asm volatile("s_waitcnt vmcnt(16)" ::: "memory");   // W's 20 (oldest) have landed
    __syncthreads();                                     // all waves' W visible

    const float* wqbase = Wl + w * 128;

    auto compute = [&](int ch, int p) {
        const float* xb = (const float*)((char*)smem + XBUF_OFF + (size_t)((w * 2 + p) * 8192));
        const float* wq = wqbase + ch * 8;
#pragma unroll
        for (int q = 0; q < 2; ++q) {
            v4f xr[4];
#pragma unroll
            for (int r = 0; r < 4; ++r)
                xr[r] = *(const v4f*)(xb + (size_t)(q * 256 + r * 64 + lane) * 4);
#pragma unroll
            for (int c = 0; c < NCOL; ++c) {
                const v4f w4 = *(const v4f*)(wq + (size_t)c * ND + q * 4);  // uniform broadcast
#pragma unroll
                for (int r = 0; r < 4; ++r) {
                    float a = acc[r][c];
                    a = fmaf(xr[r].x, w4.x, a);
                    a = fmaf(xr[r].y, w4.y, a);
                    a = fmaf(xr[r].z, w4.z, a);
                    a = fmaf(xr[r].w, w4.w, a);
                    acc[r][c] = a;
                }
            }
        }
    };

    // 16 chunks of 8 d; double-buffered, counted vmcnt, NO barriers in loop
    for (int ch = 0; ch < 15; ++ch) {
        const int p = ch & 1;
        asm volatile("s_waitcnt vmcnt(8)" ::: "memory");    // chunk ch landed (next-chunk 8 stay in flight)
        __builtin_amdgcn_sched_barrier(0);
        compute(ch, p);
        if (ch < 14) {
            asm volatile("s_waitcnt lgkmcnt(0)" ::: "memory");  // ch's ds_reads done before overwrite
            __builtin_amdgcn_sched_barrier(0);
            stage_x(ch + 2, p);
        }
    }
    asm volatile("s_waitcnt vmcnt(0)" ::: "memory");
    __builtin_amdgcn_sched_barrier(0);
    compute(15, 1);

    // ---- deterministic cross-wave combine (A = q0+q2, B = q1+q3) ----
    __syncthreads();
    float* A  = (float*)smem;
    float* Bf = (float*)((char*)smem + BBUF_OFF);
    if (w < 2) {
        float* D = (w == 0) ? A : Bf;
#pragma unroll
        for (int r = 0; r < 4; ++r) {
            float* Dr = D + (size_t)(r * 64 + lane) * ACC_STRIDE;
#pragma unroll
            for (int c4 = 0; c4 < 10; ++c4) {
                v4f v = {acc[r][c4*4+0], acc[r][c4*4+1], acc[r][c4*4+2], acc[r][c4*4+3]};
                *(v4f*)(Dr + c4 * 4) = v;
            }
        }
    }
    __syncthreads();
    if (w >= 2) {
        float* D = (w == 2) ? A : Bf;
#pragma unroll
        for (int r = 0; r < 4; ++r) {
            float* Dr = D + (size_t)(r * 64 + lane) * ACC_STRIDE;
#pragma unroll
            for (int c4 = 0; c4 < 10; ++c4) {
                v4f v = *(const v4f*)(Dr + c4 * 4);
                v.x += acc[r][c4*4+0]; v.y += acc[r][c4*4+1];
                v.z += acc[r][c4*4+2]; v.w += acc[r][c4*4+3];
                *(v4f*)(Dr + c4 * 4) = v;
            }
        }
    }
    __syncthreads();

    // ---- epilogue: wave w owns rows [w*64, w*64+64), lane -> one row ----
    const int rowb = w * 64 + lane;
    float l[NCOL];
#pragma unroll
    for (int c4 = 0; c4 < 10; ++c4) {
        v4f a = *(const v4f*)(A  + (size_t)rowb * ACC_STRIDE + c4 * 4);
        v4f b = *(const v4f*)(Bf + (size_t)rowb * ACC_STRIDE + c4 * 4);
        l[c4*4+0] = a.x + b.x; l[c4*4+1] = a.y + b.y;
        l[c4*4+2] = a.z + b.z; l[c4*4+3] = a.w + b.w;
    }

    constexpr int TOWN[10] = {0,1,2,2,2,3,3,3,4,4};
    constexpr int FOWN[25] = {0,1,2,2,2,3,3,3,3,3,3,3,3,4,9,6,8,5,7,1,3,3,3,9,3};

    float gl[5]; int gp = 0; float gbest = -INFINITY;
#pragma unroll
    for (int c = 0; c < 5; ++c) {
        float v = l[c] + bg[c];
        gl[c] = v;
        if (v > gbest) { gbest = v; gp = c; }   // strict > == jnp.argmax first-max
    }
    float tl[10]; int tp = 0; float tbest = -INFINITY;
#pragma unroll
    for (int k = 0; k < 10; ++k) {
        float v = (l[5 + k] + bt[k]) * ((TOWN[k] == gp) ? 1.f : 0.f);
        tl[k] = v;
        if (v > tbest) { tbest = v; tp = k; }
    }
    float fl[25];
#pragma unroll
    for (int f = 0; f < 25; ++f) {
        fl[f] = (l[15 + f] + bf[f]) * ((FOWN[f] == tp) ? 1.f : 0.f);
    }

    const int r  = row0 + rowb;
    const int b  = r >> 12;        // / 4096
    const int tt = r & (NTF - 1);  // % 4096

    // group_up [B][S][5]: 2 frames x 5 -> 5x float2
    {
        v2f* og = (v2f*)(out + ((size_t)b * NS + 2 * (size_t)tt) * 5);
#pragma unroll
        for (int j = 0; j < 5; ++j) {
            v2f v; v.x = gl[(2 * j) % 5]; v.y = gl[(2 * j + 1) % 5];
            og[j] = v;
        }
    }
    // tech_up [B][S][10]: 2 frames x 10 -> 5x float4
    {
        v4f* ot = (v4f*)(out + (size_t)NB * NS * 5 + ((size_t)b * NS + 2 * (size_t)tt) * 10);
#pragma unroll
        for (int j = 0; j < 5; ++j) {
            v4f v;
            v.x = tl[(4 * j)     % 10];
            v.y = tl[(4 * j + 1) % 10];
            v.z = tl[(4 * j + 2) % 10];
            v.w = tl[(4 * j + 3) % 10];
            ot[j] = v;
        }
    }
    // final_up [B][S][25]: 2 frames x 25 -> 25x float2
    {
        v2f* of = (v2f*)(out + (size_t)NB * NS * 15 + ((size_t)b * NS + 2 * (size_t)tt) * 25);
#pragma unroll
        for (int j = 0; j < 25; ++j) {
            v2f v; v.x = fl[(2 * j) % 25]; v.y = fl[(2 * j + 1) % 25];
            of[j] = v;
        }
    }
    // frame_level_final_tech_logits [B][T][25]
    {
        float* ofr = out + (size_t)NB * NS * 40 + ((size_t)b * NTF + tt) * 25;
#pragma unroll
        for (int i = 0; i < 25; ++i) ofr[i] = fl[i];
    }
}

extern "C" void kernel_launch(void* const* d_in, const int* in_sizes, int n_in,
                              void* d_out, int out_size, void* d_ws, size_t ws_size,
                              hipStream_t stream)
{
    const float* x  = (const float*)d_in[0];
    const float* Wg = (const float*)d_in[1];
    const float* bg = (const float*)d_in[2];
    const float* Wt = (const float*)d_in[3];
    const float* bt = (const float*)d_in[4];
    const float* Wf = (const float*)d_in[5];
    const float* bf = (const float*)d_in[6];
    float* Wp   = (float*)d_ws;          // 40*512*4 = 80 KB packed weights
    float* outp = (float*)d_out;

    hipLaunchKernelGGL(pack_w_kernel, dim3((NCOL * ND + 255) / 256), dim3(256), 0, stream,
                       Wg, Wt, Wf, Wp);
    hipLaunchKernelGGL(hier_main, dim3((NB * NTF) / 256), dim3(256), 0, stream,
                       x, bg, bt, bf, Wp, outp);
}